// Round 4
// baseline (305.352 us; speedup 1.0000x reference)
//
#include <hip/hip_runtime.h>

// ReActNet BasicBlock forward:
//   out = BN(binary_conv3x3(sign(x), scale*sign(w))) + x
// XNOR-popcount conv, 4 output pixels per thread (shared 3x6 tap window in
// VGPRs), 32-channel o-split per block. Weights via wave-uniform s_loads.
// Zero padding folded into per-(border-pattern,o) bias table in LDS; exact
// x==0 handled by rare masked slow path.

#define N_   64
#define C_   128
#define H_   56
#define W_   56
#define HW_  (H_*W_)       // 3136
#define PH_  (H_+2)        // 58
#define PW_  (W_+2)        // 58
#define PHW_ (PH_*PW_)     // 3364
#define NPIX (N_*HW_)      // 200704
#define NPAD (N_*PHW_)     // 215296
#define NGRP (NPIX/4)      // 50176 4-pixel groups
#define GPI  (HW_/4)       // 784 groups per image
#define GPR  (W_/4)        // 14 groups per row

typedef unsigned long long u64;

// ---------------------------------------------------------------------------
// Kernel 1: weight prep. One wave per output channel.
//   wbits layout: [o][tap][j] (18 u64 per o, contiguous)
//   A = scale*gamma*rsqrt(var+eps); B = beta - mean*...; A2 = -2A
// ---------------------------------------------------------------------------
__global__ void prep_w_kernel(const float* __restrict__ w,
                              const float* __restrict__ gamma,
                              const float* __restrict__ beta,
                              const float* __restrict__ bn_mean,
                              const float* __restrict__ bn_var,
                              u64* __restrict__ wbits,
                              float* __restrict__ A, float* __restrict__ B,
                              float* __restrict__ A2) {
    const int o = blockIdx.x;
    const int lane = threadIdx.x;          // 0..63
    const float* wo = w + o * 1152;        // [i][kh][kw] flat, i*9 + tap

    float s = 0.f;
    #pragma unroll
    for (int k = 0; k < 18; k++) s += fabsf(wo[k * 64 + lane]);
    #pragma unroll
    for (int off = 32; off > 0; off >>= 1) s += __shfl_down(s, off);
    float scale = __shfl(s, 0) * (1.0f / 1152.0f);

    #pragma unroll
    for (int t = 0; t < 9; t++) {
        #pragma unroll
        for (int j = 0; j < 2; j++) {
            float v = wo[(j * 64 + lane) * 9 + t];
            u64 b = __ballot(v < 0.0f);
            if (lane == 0) wbits[(o * 9 + t) * 2 + j] = b;
        }
    }
    if (lane == 0) {
        float inv = gamma[o] * rsqrtf(bn_var[o] + 1e-5f);
        float a = scale * inv;
        A[o] = a;
        B[o] = beta[o] - bn_mean[o] * inv;
        A2[o] = -2.0f * a;
    }
}

// ---------------------------------------------------------------------------
// Kernel 2: binarize x, 4 pixels per thread (float4 loads).
// ---------------------------------------------------------------------------
__global__ __launch_bounds__(128) void pack_x_kernel(
        const float* __restrict__ x,
        ulonglong2* __restrict__ xbs,
        ulonglong2* __restrict__ xbz,
        unsigned* __restrict__ xcnt) {
    int t = blockIdx.x * 128 + threadIdx.x;     // 0..NGRP-1
    int n   = t / GPI;
    int rem = t - n * GPI;
    int h   = rem / GPR;
    int wg  = rem - h * GPR;
    int w   = wg * 4;

    const float4* xp = (const float4*)(x + (size_t)n * C_ * HW_ + h * W_ + w);

    unsigned sg[4][4], nz[4][4];
    #pragma unroll
    for (int p = 0; p < 4; p++)
        #pragma unroll
        for (int j = 0; j < 4; j++) { sg[p][j] = 0; nz[p][j] = 0; }

    #pragma unroll
    for (int j = 0; j < 4; j++) {
        #pragma unroll 8
        for (int c = 0; c < 32; c++) {
            float4 v = xp[(size_t)(j * 32 + c) * (HW_ / 4)];
            unsigned u0 = __float_as_uint(v.x), u1 = __float_as_uint(v.y);
            unsigned u2 = __float_as_uint(v.z), u3 = __float_as_uint(v.w);
            sg[0][j] |= (u0 >> 31) << c; nz[0][j] |= ((u0 << 1) != 0u ? 1u : 0u) << c;
            sg[1][j] |= (u1 >> 31) << c; nz[1][j] |= ((u1 << 1) != 0u ? 1u : 0u) << c;
            sg[2][j] |= (u2 >> 31) << c; nz[2][j] |= ((u2 << 1) != 0u ? 1u : 0u) << c;
            sg[3][j] |= (u3 >> 31) << c; nz[3][j] |= ((u3 << 1) != 0u ? 1u : 0u) << c;
        }
    }

    int pg = (n * PH_ + h + 1) * PW_ + (w + 1);
    #pragma unroll
    for (int p = 0; p < 4; p++) {
        ulonglong2 s2, z2;
        s2.x = (u64)sg[p][0] | ((u64)sg[p][1] << 32);
        s2.y = (u64)sg[p][2] | ((u64)sg[p][3] << 32);
        z2.x = (u64)nz[p][0] | ((u64)nz[p][1] << 32);
        z2.y = (u64)nz[p][2] | ((u64)nz[p][3] << 32);
        xbs[pg + p] = s2;
        xbz[pg + p] = z2;
        xcnt[pg + p] = __popc(nz[p][0]) + __popc(nz[p][1]) +
                       __popc(nz[p][2]) + __popc(nz[p][3]);
    }
}

// ---------------------------------------------------------------------------
// Kernel 2b: zero the padded border entries.
// ---------------------------------------------------------------------------
__global__ void border_kernel(ulonglong2* __restrict__ xbs,
                              ulonglong2* __restrict__ xbz,
                              unsigned* __restrict__ xcnt) {
    int bt = blockIdx.x * 256 + threadIdx.x;
    if (bt >= N_ * 228) return;                 // 2*58 + 2*56 = 228 per image
    int n = bt / 228, e = bt - n * 228;
    int ph, pw;
    if (e < 58)       { ph = 0;  pw = e; }
    else if (e < 116) { ph = 57; pw = e - 58; }
    else { int i = e - 116; ph = 1 + (i >> 1); pw = (i & 1) ? 57 : 0; }
    int g = (n * PH_ + ph) * PW_ + pw;
    ulonglong2 zz; zz.x = 0; zz.y = 0;
    xbs[g] = zz; xbz[g] = zz; xcnt[g] = 0;
}

// ---------------------------------------------------------------------------
// Kernel 3: XNOR-popcount conv + BN + residual. 4 px/thread, 32 o/block.
// ---------------------------------------------------------------------------
__device__ __forceinline__ int tapmask_of(int idx) {
    int tm = 0;
    if (idx & 1) tm |= 0x007;   // top row padded
    if (idx & 2) tm |= 0x1C0;   // bottom row padded
    if (idx & 4) tm |= 0x049;   // left col padded
    if (idx & 8) tm |= 0x124;   // right col padded
    return tm;
}

__global__ __launch_bounds__(256, 4) void bconv_kernel(
        const ulonglong2* __restrict__ xbs,
        const ulonglong2* __restrict__ xbz,
        const unsigned*   __restrict__ xcnt,
        const u64* __restrict__ wbits,          // [128][18] u64
        const float* __restrict__ Ag, const float* __restrict__ Bg,
        const float* __restrict__ A2g,
        const float* __restrict__ x, float* __restrict__ out) {
    __shared__ float Bf_s[16 * 32];             // folded bias, 2 KiB

    const int tid = threadIdx.x;
    const int obase = blockIdx.y * 32;

    // Bf[pidx][o] = A*(1152 - padsum(pidx,o)) + B
    for (int e = tid; e < 512; e += 256) {
        int pidx = e >> 5, o = e & 31;
        int tm = tapmask_of(pidx);
        const u64* wp = wbits + (size_t)(obase + o) * 18;
        int s = 0;
        #pragma unroll
        for (int tp = 0; tp < 9; tp++) {
            if ((tm >> tp) & 1)
                s += 128 - 2 * (__popcll(wp[2*tp]) + __popcll(wp[2*tp+1]));
        }
        float a = Ag[obase + o];
        Bf_s[e] = fmaf(a, (float)(1152 - s), Bg[obase + o]);
    }
    __syncthreads();

    int t = blockIdx.x * 256 + tid;             // 0..NGRP-1
    int n   = t / GPI;
    int rem = t - n * GPI;
    int h   = rem / GPR;
    int wg  = rem - h * GPR;
    int w   = wg * 4;

    // Load 3x6 tap window (s-words) + nonzero counts.
    u64 S0[3][6], S1[3][6];
    unsigned cnt[3][6];
    int rowg[3];
    #pragma unroll
    for (int dh = 0; dh < 3; dh++) {
        int base = (n * PH_ + h + dh) * PW_ + w;   // leftmost tap col
        rowg[dh] = base;
        #pragma unroll
        for (int j = 0; j < 6; j++) {
            ulonglong2 v = xbs[base + j];
            S0[dh][j] = v.x; S1[dh][j] = v.y;
        }
        #pragma unroll
        for (int j = 0; j < 3; j++) {
            uint2 c2 = *(const uint2*)&xcnt[base + 2*j];
            cnt[dh][2*j] = c2.x; cnt[dh][2*j+1] = c2.y;
        }
    }

    int pidxs[4];
    bool fastall = true;
    #pragma unroll
    for (int p = 0; p < 4; p++) {
        int ww = w + p;
        int pidx = (h == 0 ? 1 : 0) | (h == H_-1 ? 2 : 0) |
                   (ww == 0 ? 4 : 0) | (ww == W_-1 ? 8 : 0);
        pidxs[p] = pidx;
        int valid = 9 - __popc(tapmask_of(pidx));
        int cs = 0;
        #pragma unroll
        for (int dh = 0; dh < 3; dh++)
            cs += cnt[dh][p] + cnt[dh][p+1] + cnt[dh][p+2];
        fastall = fastall && (cs == 128 * valid);
    }

    size_t pixoff = (size_t)(n * C_ + obase) * HW_ + h * W_ + w;
    const float4* xr = (const float4*)(x + pixoff);
    float4*       op = (float4*)(out + pixoff);
    const int step4 = HW_ / 4;

    if (fastall) {
        const u64* wp = wbits + (size_t)obase * 18;
        const float* bf0 = &Bf_s[pidxs[0] << 5];
        const float* bf1 = &Bf_s[pidxs[1] << 5];
        const float* bf2 = &Bf_s[pidxs[2] << 5];
        const float* bf3 = &Bf_s[pidxs[3] << 5];
        for (int o = 0; o < 32; o++) {
            int pc0 = 0, pc1 = 0, pc2 = 0, pc3 = 0;
            #pragma unroll
            for (int dh = 0; dh < 3; dh++) {
                #pragma unroll
                for (int dw = 0; dw < 3; dw++) {
                    u64 w0 = wp[(dh*3+dw)*2], w1 = wp[(dh*3+dw)*2+1];
                    pc0 += __popcll(S0[dh][0+dw] ^ w0) + __popcll(S1[dh][0+dw] ^ w1);
                    pc1 += __popcll(S0[dh][1+dw] ^ w0) + __popcll(S1[dh][1+dw] ^ w1);
                    pc2 += __popcll(S0[dh][2+dw] ^ w0) + __popcll(S1[dh][2+dw] ^ w1);
                    pc3 += __popcll(S0[dh][3+dw] ^ w0) + __popcll(S1[dh][3+dw] ^ w1);
                }
            }
            wp += 18;
            float a2 = A2g[obase + o];          // wave-uniform -> s_load
            float4 r = xr[(size_t)o * step4];
            float4 v;
            v.x = fmaf(a2, (float)pc0, bf0[o]) + r.x;
            v.y = fmaf(a2, (float)pc1, bf1[o]) + r.y;
            v.z = fmaf(a2, (float)pc2, bf2[o]) + r.z;
            v.w = fmaf(a2, (float)pc3, bf3[o]) + r.w;
            op[(size_t)o * step4] = v;
        }
    } else {
        // rare: some exact-zero x in the window -> masked popcount per pixel
        #pragma unroll 1
        for (int p = 0; p < 4; p++) {
            u64 Z0[3][3], Z1[3][3];
            int cs = 0;
            #pragma unroll
            for (int dh = 0; dh < 3; dh++) {
                #pragma unroll
                for (int dw = 0; dw < 3; dw++) {
                    int gi = rowg[dh] + p + dw;
                    ulonglong2 z = xbz[gi];
                    Z0[dh][dw] = z.x; Z1[dh][dw] = z.y;
                    cs += (int)xcnt[gi];
                }
            }
            const u64* wp = wbits + (size_t)obase * 18;
            #pragma unroll 1
            for (int o = 0; o < 32; o++) {
                int pc = 0;
                #pragma unroll
                for (int dh = 0; dh < 3; dh++) {
                    #pragma unroll
                    for (int dw = 0; dw < 3; dw++) {
                        u64 w0 = wp[(dh*3+dw)*2], w1 = wp[(dh*3+dw)*2+1];
                        pc += __popcll((S0[dh][p+dw] ^ w0) & Z0[dh][dw]);
                        pc += __popcll((S1[dh][p+dw] ^ w1) & Z1[dh][dw]);
                    }
                }
                wp += 18;
                float a = Ag[obase + o], b = Bg[obase + o];
                size_t off = pixoff + (size_t)o * HW_ + p;
                out[off] = fmaf(a, (float)(cs - 2 * pc), b) + x[off];
            }
        }
    }
}

// ---------------------------------------------------------------------------
extern "C" void kernel_launch(void* const* d_in, const int* in_sizes, int n_in,
                              void* d_out, int out_size, void* d_ws, size_t ws_size,
                              hipStream_t stream) {
    const float* x      = (const float*)d_in[0];
    const float* weight = (const float*)d_in[1];
    const float* gamma  = (const float*)d_in[2];
    const float* beta   = (const float*)d_in[3];
    const float* bnmean = (const float*)d_in[4];
    const float* bnvar  = (const float*)d_in[5];
    float* out = (float*)d_out;

    char* ws = (char*)d_ws;
    u64*        wbits = (u64*)ws;                          // 18432 B
    float*      A     = (float*)(ws + 18432);              // 512 B
    float*      B     = (float*)(ws + 18944);              // 512 B
    float*      A2    = (float*)(ws + 19456);              // 512 B
    ulonglong2* xbs   = (ulonglong2*)(ws + 19968);                        // NPAD*16
    ulonglong2* xbz   = (ulonglong2*)(ws + 19968 + (size_t)NPAD * 16);    // NPAD*16
    unsigned*   xcnt  = (unsigned*)(ws + 19968 + (size_t)NPAD * 32);      // NPAD*4
    // total ws use: ~7.77 MB

    prep_w_kernel<<<128, 64, 0, stream>>>(weight, gamma, beta, bnmean, bnvar,
                                          wbits, A, B, A2);
    pack_x_kernel<<<NGRP / 128, 128, 0, stream>>>(x, xbs, xbz, xcnt);
    border_kernel<<<(N_ * 228 + 255) / 256, 256, 0, stream>>>(xbs, xbz, xcnt);
    dim3 cgrid(NGRP / 256, 4);
    bconv_kernel<<<cgrid, 256, 0, stream>>>(xbs, xbz, xcnt, wbits, A, B, A2,
                                            x, out);
}